// Round 8
// baseline (985.270 us; speedup 1.0000x reference)
//
#include <hip/hip_runtime.h>
#include <math.h>

constexpr int IN_DIM = 1433;
constexpr int HID    = 16;
constexpr int OUTD   = 7;

// ---------- edge index access (int32 vs int64 auto-detect) ----------
__device__ __forceinline__ int edge_get(const int* __restrict__ ei, long long idx, int is64) {
    return is64 ? ei[2 * idx] : ei[idx];
}

__global__ void k_detect(const int* __restrict__ ei, int* __restrict__ flag) {
    __shared__ int nzsh;
    if (threadIdx.x == 0) nzsh = 0;
    __syncthreads();
    int nz = 0;
    for (int i = threadIdx.x; i < 2048; i += blockDim.x)
        nz |= (ei[2 * i + 1] != 0) ? 1 : 0;
    if (nz) nzsh = 1;
    __syncthreads();
    if (threadIdx.x == 0) *flag = (nzsh == 0) ? 1 : 0;   // 1 => int64
}

// ---------- init ----------
__global__ void k_init_new(int* __restrict__ deg, int* __restrict__ cnt, int n) {
    int i = blockIdx.x * blockDim.x + threadIdx.x;
    if (i < n) { deg[i] = 1; cnt[i] = 0; }
}

__global__ void k_deg_finish(float* __restrict__ dis, int n) {
    int i = blockIdx.x * blockDim.x + threadIdx.x;
    if (i < n) {
        int v = ((const int*)dis)[i];
        dis[i] = rsqrtf((float)v);
    }
}

// ---------- FUSED: histogram (blocks < nHist) + GEMM1 (remaining blocks) ----------
// GEMM: h1 = x @ W1 + b1 (raw). NO LDS, NO barriers. 256 threads; thread
// (c4 = t&3, rr = t>>2) computes rows {row0+rr, row0+rr+64} x cols c4*4..+3.
// x read global->reg as float4 along own rows (16B/lane; 64B lines reused 4x
// via L1). W1 (91.7 KB) is L2/L3-hot: per k one float4; lanes c4=0..3 form a
// coalesced 64B segment, broadcast across the 16 row-groups of the wave.
// Occupancy ~VGPR-bound; deep TLP hides x-load latency; LDS-issue ceiling gone.
// Hist: grid-stride, fire-and-forget int atomics (memory-side throughput-bound),
// runs concurrently on the same CUs.
__global__ __launch_bounds__(256) void k_gemm1h(
        const float* __restrict__ x, const float* __restrict__ W1,
        const float* __restrict__ b1, float* __restrict__ h1, int n,
        const int* __restrict__ ei, int E, const int* __restrict__ flag,
        int* __restrict__ deg, int* __restrict__ cnt, int nHist) {
    if ((int)blockIdx.x < nHist) {
        int is64 = *flag;
        long long stride = (long long)nHist * blockDim.x;
        for (long long e = (long long)blockIdx.x * blockDim.x + threadIdx.x;
             e < E; e += stride) {
            int s = edge_get(ei, e, is64);
            int d = edge_get(ei, (long long)E + e, is64);
            atomicAdd(&deg[s], 1);   // out-degree on src (reference semantics)
            atomicAdd(&cnt[d], 1);   // CSR bucket sizes by dst
        }
        return;
    }

    const int t    = threadIdx.x;
    const int c4   = t & 3;
    const int rr   = t >> 2;                       // 0..63
    const int row0 = ((int)blockIdx.x - nHist) * 128;
    const int ra   = row0 + rr;
    const int rb   = ra + 64;
    const bool va  = ra < n;
    const bool vb  = rb < n;
    const float* pa = x + (long long)(va ? ra : (n - 1)) * IN_DIM;
    const float* pb = x + (long long)(vb ? rb : (n - 1)) * IN_DIM;
    const float* pw = W1 + c4 * 4;                 // row k at pw[k*16], 16B aligned

    float4 aa = make_float4(0.f, 0.f, 0.f, 0.f);
    float4 ab = make_float4(0.f, 0.f, 0.f, 0.f);

    int k = 0;
    #pragma unroll 4
    for (; k + 4 <= IN_DIM; k += 4) {
        float4 xa = *(const float4*)(pa + k);      // 4B-aligned dwordx4 (ok, proven R5)
        float4 xb = *(const float4*)(pb + k);
        float4 w0 = *(const float4*)(pw + (long long)(k + 0) * HID);
        float4 w1 = *(const float4*)(pw + (long long)(k + 1) * HID);
        float4 w2 = *(const float4*)(pw + (long long)(k + 2) * HID);
        float4 w3 = *(const float4*)(pw + (long long)(k + 3) * HID);
        aa.x += xa.x * w0.x + xa.y * w1.x + xa.z * w2.x + xa.w * w3.x;
        aa.y += xa.x * w0.y + xa.y * w1.y + xa.z * w2.y + xa.w * w3.y;
        aa.z += xa.x * w0.z + xa.y * w1.z + xa.z * w2.z + xa.w * w3.z;
        aa.w += xa.x * w0.w + xa.y * w1.w + xa.z * w2.w + xa.w * w3.w;
        ab.x += xb.x * w0.x + xb.y * w1.x + xb.z * w2.x + xb.w * w3.x;
        ab.y += xb.x * w0.y + xb.y * w1.y + xb.z * w2.y + xb.w * w3.y;
        ab.z += xb.x * w0.z + xb.y * w1.z + xb.z * w2.z + xb.w * w3.z;
        ab.w += xb.x * w0.w + xb.y * w1.w + xb.z * w2.w + xb.w * w3.w;
    }
    for (; k < IN_DIM; ++k) {                      // 1433 = 4*358 + 1
        float4 w0 = *(const float4*)(pw + (long long)k * HID);
        float xa = pa[k], xb = pb[k];
        aa.x += xa * w0.x; aa.y += xa * w0.y; aa.z += xa * w0.z; aa.w += xa * w0.w;
        ab.x += xb * w0.x; ab.y += xb * w0.y; ab.z += xb * w0.z; ab.w += xb * w0.w;
    }

    float4 bv = *(const float4*)&b1[c4 * 4];
    if (va) {
        float4 hv;
        hv.x = aa.x + bv.x; hv.y = aa.y + bv.y; hv.z = aa.z + bv.z; hv.w = aa.w + bv.w;
        *(float4*)&h1[(long long)ra * HID + c4 * 4] = hv;
    }
    if (vb) {
        float4 hv;
        hv.x = ab.x + bv.x; hv.y = ab.y + bv.y; hv.z = ab.z + bv.z; hv.w = ab.w + bv.w;
        *(float4*)&h1[(long long)rb * HID + c4 * 4] = hv;
    }
}

// ---------- scale: out = dis[row]^(1|2) * in  (elementwise, float4) ----------
__global__ void k_scale(const float* __restrict__ dis, const float* __restrict__ in,
                        float* __restrict__ out, int n, int squared) {
    int i = blockIdx.x * blockDim.x + threadIdx.x;   // one float4 per thread
    if (i >= n * 4) return;
    int row = i >> 2;
    float d = dis[row];
    if (squared) d *= d;
    float4 v = *(const float4*)&in[(long long)i * 4];
    v.x *= d; v.y *= d; v.z *= d; v.w *= d;
    *(float4*)&out[(long long)i * 4] = v;
}

// ---------- 3-kernel exclusive scan of cnt[0..n) -> row_ptr, cursor ----------
__global__ __launch_bounds__(256) void k_scan1(const int* __restrict__ cnt,
                                               int* __restrict__ bsum, int n) {
    __shared__ int sh[256];
    int t = threadIdx.x;
    int base = blockIdx.x * 1024 + t * 4;
    int s = 0;
    #pragma unroll
    for (int j = 0; j < 4; ++j) {
        int i = base + j;
        if (i < n) s += cnt[i];
    }
    sh[t] = s; __syncthreads();
    for (int o = 128; o > 0; o >>= 1) {
        if (t < o) sh[t] += sh[t + o];
        __syncthreads();
    }
    if (t == 0) bsum[blockIdx.x] = sh[0];
}

__global__ __launch_bounds__(256) void k_scan2(const int* __restrict__ bsum,
                                               int* __restrict__ boff,
                                               int* __restrict__ rp,
                                               int nb, int n, int E) {
    __shared__ int sh[256];
    int t = threadIdx.x;
    int v = (t < nb) ? bsum[t] : 0;
    sh[t] = v; __syncthreads();
    for (int o = 1; o < 256; o <<= 1) {
        int tmp = (t >= o) ? sh[t - o] : 0;
        __syncthreads();
        sh[t] += tmp;
        __syncthreads();
    }
    boff[t] = sh[t] - v;     // exclusive
    if (t == 0) rp[n] = E;   // total
}

__global__ __launch_bounds__(256) void k_scan3(const int* __restrict__ cnt,
                                               const int* __restrict__ boff,
                                               int* __restrict__ rp,
                                               int* __restrict__ cur, int n) {
    __shared__ int sh[256];
    int t = threadIdx.x;
    int base = blockIdx.x * 1024 + t * 4;
    int c[4];
    int s = 0;
    #pragma unroll
    for (int j = 0; j < 4; ++j) {
        int i = base + j;
        c[j] = (i < n) ? cnt[i] : 0;
        s += c[j];
    }
    sh[t] = s; __syncthreads();
    for (int o = 1; o < 256; o <<= 1) {
        int tmp = (t >= o) ? sh[t - o] : 0;
        __syncthreads();
        sh[t] += tmp;
        __syncthreads();
    }
    int run = boff[blockIdx.x] + sh[t] - s;
    #pragma unroll
    for (int j = 0; j < 4; ++j) {
        int i = base + j;
        if (i < n) { rp[i] = run; cur[i] = run; }
        run += c[j];
    }
}

__global__ void k_fill(const int* __restrict__ ei, int E, const int* __restrict__ flag,
                       int* __restrict__ cur, int* __restrict__ csr) {
    int e = blockIdx.x * blockDim.x + threadIdx.x;
    if (e >= E) return;
    int is64 = *flag;
    int s = edge_get(ei, e, is64);
    int d = edge_get(ei, (long long)E + e, is64);
    int slot = atomicAdd(&cur[d], 1);
    csr[slot] = s;
}

// ---------- fused gather1 + gemm2 (pre-scaled inputs) ----------
__global__ __launch_bounds__(256) void k_gather1f(
        const int* __restrict__ rp, const int* __restrict__ csr,
        const float* __restrict__ dis, const float* __restrict__ hs1,
        const float* __restrict__ W2, const float* __restrict__ b2,
        float* __restrict__ hs2, int n) {
    __shared__ float w2s[HID * OUTD];
    __shared__ float b2s[OUTD];
    int t = threadIdx.x;
    if (t < HID * OUTD) w2s[t] = W2[t];
    if (t < OUTD) b2s[t] = b2[t];
    __syncthreads();

    int tid  = blockIdx.x * blockDim.x + t;
    int node = tid >> 2;
    int q    = tid & 3;
    if (node >= n) return;

    float4 acc = *(const float4*)&hs1[(long long)node * HID + q * 4];  // self term

    int i = rp[node], end = rp[node + 1];
    if (i < end) {
        int    s1  = csr[i];
        float4 hv1 = *(const float4*)&hs1[(long long)s1 * HID + q * 4];
        for (++i; i < end; ++i) {
            int    s2  = csr[i];
            float4 hv2 = *(const float4*)&hs1[(long long)s2 * HID + q * 4];
            acc.x += hv1.x; acc.y += hv1.y; acc.z += hv1.z; acc.w += hv1.w;
            hv1 = hv2;
        }
        acc.x += hv1.x; acc.y += hv1.y; acc.z += hv1.z; acc.w += hv1.w;
    }

    float dn = dis[node];
    float r0 = fmaxf(dn * acc.x, 0.f), r1 = fmaxf(dn * acc.y, 0.f);
    float r2 = fmaxf(dn * acc.z, 0.f), r3 = fmaxf(dn * acc.w, 0.f);
    float p[OUTD];
    #pragma unroll
    for (int j = 0; j < OUTD; ++j) {
        p[j] = r0 * w2s[(q * 4 + 0) * OUTD + j]
             + r1 * w2s[(q * 4 + 1) * OUTD + j]
             + r2 * w2s[(q * 4 + 2) * OUTD + j]
             + r3 * w2s[(q * 4 + 3) * OUTD + j];
    }
    #pragma unroll
    for (int j = 0; j < OUTD; ++j) {
        p[j] += __shfl_xor(p[j], 1, 4);
        p[j] += __shfl_xor(p[j], 2, 4);
    }
    hs2[(long long)node * OUTD + q] = dn * (p[q] + b2s[q]);
    if (q < 3) hs2[(long long)node * OUTD + q + 4] = dn * (p[q + 4] + b2s[q + 4]);
}

// ---------- gather2 + log_softmax fused (pre-scaled, 1-ahead pipelined) ----------
__global__ __launch_bounds__(256) void k_gather2(
        const int* __restrict__ rp, const int* __restrict__ csr,
        const float* __restrict__ dis, const float* __restrict__ hs2,
        float* __restrict__ out, int n) {
    int t = threadIdx.x;
    int node = blockIdx.x * 32 + (t >> 3);
    int q = t & 7;
    if (node >= n) return;
    float acc = -1e30f;
    if (q < OUTD) {
        acc = hs2[(long long)node * OUTD + q];   // self term
        int i = rp[node], end = rp[node + 1];
        if (i < end) {
            int   s1 = csr[i];
            float v1 = hs2[(long long)s1 * OUTD + q];
            for (++i; i < end; ++i) {
                int   s2 = csr[i];
                float v2 = hs2[(long long)s2 * OUTD + q];
                acc += v1;
                v1 = v2;
            }
            acc += v1;
        }
        acc *= dis[node];
    }
    float m = acc;
    #pragma unroll
    for (int o = 1; o < 8; o <<= 1) m = fmaxf(m, __shfl_xor(m, o, 8));
    float ex = (q < OUTD) ? expf(acc - m) : 0.f;
    float ss = ex;
    #pragma unroll
    for (int o = 1; o < 8; o <<= 1) ss += __shfl_xor(ss, o, 8);
    if (q < OUTD) out[(long long)node * OUTD + q] = acc - m - logf(ss);
}

// ---------- fallback-only kernels (atomic path) ----------
__global__ void k_deg_init(int* __restrict__ deg, int n) {
    int i = blockIdx.x * blockDim.x + threadIdx.x;
    if (i < n) deg[i] = 1;
}

__global__ void k_deg_count(const int* __restrict__ ei, int E,
                            const int* __restrict__ flag, int* __restrict__ deg) {
    int e = blockIdx.x * blockDim.x + threadIdx.x;
    if (e >= E) return;
    int is64 = *flag;
    int s = edge_get(ei, e, is64);
    atomicAdd(&deg[s], 1);
}

__global__ void k_agg1(const int* __restrict__ ei, int E, const int* __restrict__ flag,
                       const float* __restrict__ dis, const float* __restrict__ h1,
                       float* __restrict__ a1) {
    long long tid = (long long)blockIdx.x * blockDim.x + threadIdx.x;
    int e = (int)(tid >> 2);
    int q = (int)(tid & 3);
    if (e >= E) return;
    int is64 = *flag;
    int s = edge_get(ei, e, is64);
    int d = edge_get(ei, (long long)E + e, is64);
    float nrm = dis[s] * dis[d];
    float4 v = *(const float4*)&h1[(long long)s * HID + q * 4];
    float* o = &a1[(long long)d * HID + q * 4];
    atomicAdd(o + 0, nrm * v.x);
    atomicAdd(o + 1, nrm * v.y);
    atomicAdd(o + 2, nrm * v.z);
    atomicAdd(o + 3, nrm * v.w);
}

__global__ __launch_bounds__(256) void k_gemm2(
        const float* __restrict__ a1, const float* __restrict__ W2,
        const float* __restrict__ b2, const float* __restrict__ dis,
        float* __restrict__ h2, float* __restrict__ a2, int n) {
    __shared__ float w2s[HID * OUTD];
    __shared__ float b2s[OUTD];
    int t = threadIdx.x;
    if (t < HID * OUTD) w2s[t] = W2[t];
    if (t < OUTD) b2s[t] = b2[t];
    __syncthreads();
    int r = blockIdx.x * blockDim.x + t;
    if (r >= n) return;
    float a[16];
    #pragma unroll
    for (int i = 0; i < 4; ++i) {
        float4 v = *(const float4*)&a1[(long long)r * HID + i * 4];
        a[4 * i + 0] = fmaxf(v.x, 0.f);
        a[4 * i + 1] = fmaxf(v.y, 0.f);
        a[4 * i + 2] = fmaxf(v.z, 0.f);
        a[4 * i + 3] = fmaxf(v.w, 0.f);
    }
    float dd = 0.f;
    if (a2) { float d = dis[r]; dd = d * d; }
    #pragma unroll
    for (int j = 0; j < OUTD; ++j) {
        float acc = b2s[j];
        #pragma unroll
        for (int k = 0; k < HID; ++k) acc += a[k] * w2s[k * OUTD + j];
        h2[(long long)r * OUTD + j] = acc;
        if (a2) a2[(long long)r * OUTD + j] = dd * acc;
    }
}

__global__ void k_agg2(const int* __restrict__ ei, int E, const int* __restrict__ flag,
                       const float* __restrict__ dis, const float* __restrict__ h2,
                       float* __restrict__ a2) {
    long long tid = (long long)blockIdx.x * blockDim.x + threadIdx.x;
    int e = (int)(tid >> 1);
    int q = (int)(tid & 1);
    if (e >= E) return;
    int is64 = *flag;
    int s = edge_get(ei, e, is64);
    int d = edge_get(ei, (long long)E + e, is64);
    float nrm = dis[s] * dis[d];
    int cnt = q ? 3 : 4;
    long long bs = (long long)s * OUTD + q * 4;
    long long bd = (long long)d * OUTD + q * 4;
    #pragma unroll
    for (int j = 0; j < 4; ++j)
        if (j < cnt) atomicAdd(&a2[bd + j], nrm * h2[bs + j]);
}

__global__ void k_lsm(const float* __restrict__ a2, float* __restrict__ out, int n) {
    int r = blockIdx.x * blockDim.x + threadIdx.x;
    if (r >= n) return;
    float v[OUTD];
    #pragma unroll
    for (int j = 0; j < OUTD; ++j) v[j] = a2[(long long)r * OUTD + j];
    float m = v[0];
    #pragma unroll
    for (int j = 1; j < OUTD; ++j) m = fmaxf(m, v[j]);
    float ssum = 0.f;
    #pragma unroll
    for (int j = 0; j < OUTD; ++j) ssum += expf(v[j] - m);
    float l = logf(ssum);
    #pragma unroll
    for (int j = 0; j < OUTD; ++j) out[(long long)r * OUTD + j] = v[j] - m - l;
}

extern "C" void kernel_launch(void* const* d_in, const int* in_sizes, int n_in,
                              void* d_out, int out_size, void* d_ws, size_t ws_size,
                              hipStream_t stream) {
    const float* x  = (const float*)d_in[0];
    const int*   ei = (const int*)d_in[1];
    const float* W1 = (const float*)d_in[2];
    const float* b1 = (const float*)d_in[3];
    const float* W2 = (const float*)d_in[4];
    const float* b2 = (const float*)d_in[5];
    float* out = (float*)d_out;

    const int N = in_sizes[0] / IN_DIM;   // 100000
    const int E = in_sizes[1] / 2;        // 3200000

    const int TPB = 256;
    const int gN  = (N + TPB - 1) / TPB;
    const int gE  = (E + TPB - 1) / TPB;
    const int gG1 = (N + 127) / 128;      // gemm blocks (256 threads, 128 rows)
    const int NB  = (N + 1023) / 1024;
    const int nHist = 512;

    float* ws = (float*)d_ws;
    size_t o = 0;
    auto take = [&](size_t cnt) { size_t r = o; o += (cnt + 127) & ~(size_t)127; return r; };

    size_t off_dis  = take((size_t)N);
    size_t off_flag = take(64);
    size_t off_cnt  = take((size_t)N);
    size_t off_rp   = take((size_t)N + 1);
    size_t off_cur  = take((size_t)N);
    size_t off_bs   = take(256);
    size_t off_bo   = take(256);
    size_t off_csr  = take((size_t)E);
    size_t off_h1   = take((size_t)N * HID);
    size_t off_h2   = take((size_t)N * OUTD);
    size_t need_new = o * sizeof(float);

    if (ws_size >= need_new) {
        float* dis  = ws + off_dis;
        int*   degi = (int*)dis;
        int*   flag = (int*)(ws + off_flag);
        int*   cnt  = (int*)(ws + off_cnt);
        int*   rp   = (int*)(ws + off_rp);
        int*   cur  = (int*)(ws + off_cur);
        int*   bs   = (int*)(ws + off_bs);
        int*   bo   = (int*)(ws + off_bo);
        int*   csr  = (int*)(ws + off_csr);
        float* h1   = ws + off_h1;   // raw h1, then scaled in-place -> hs1
        float* hs2  = ws + off_h2;

        k_detect<<<1, 256, 0, stream>>>(ei, flag);
        k_init_new<<<gN, TPB, 0, stream>>>(degi, cnt, N);
        // fused: hist (blocks 0..nHist-1) runs concurrently with the no-LDS gemm
        k_gemm1h<<<nHist + gG1, 256, 0, stream>>>(x, W1, b1, h1, N,
                                                  ei, E, flag, degi, cnt, nHist);
        k_deg_finish<<<gN, TPB, 0, stream>>>(dis, N);
        k_scan1<<<NB, 256, 0, stream>>>(cnt, bs, N);
        k_scan2<<<1, 256, 0, stream>>>(bs, bo, rp, NB, N, E);
        k_scan3<<<NB, 256, 0, stream>>>(cnt, bo, rp, cur, N);
        k_scale<<<(int)(((long long)N * 4 + TPB - 1) / TPB), TPB, 0, stream>>>(
            dis, h1, h1, N, 0);   // hs1 = dis * h1 (in-place)
        k_fill<<<gE, TPB, 0, stream>>>(ei, E, flag, cur, csr);
        k_gather1f<<<(int)(((long long)N * 4 + TPB - 1) / TPB), TPB, 0, stream>>>(
            rp, csr, dis, h1, W2, b2, hs2, N);
        k_gather2<<<(N + 31) / 32, 256, 0, stream>>>(rp, csr, dis, hs2, out, N);
    } else {
        o = 0;
        size_t f_dis  = take((size_t)N);
        size_t f_flag = take(64);
        size_t f_h1   = take((size_t)N * HID);
        size_t f_a1   = take((size_t)N * HID);
        size_t f_h2   = take((size_t)N * OUTD);
        size_t f_a2   = take((size_t)N * OUTD);

        float* dis  = ws + f_dis;
        int*   degi = (int*)dis;
        int*   flag = (int*)(ws + f_flag);
        float* h1   = ws + f_h1;
        float* a1   = ws + f_a1;
        float* h2   = ws + f_h2;
        float* a2   = ws + f_a2;

        int g4E = (int)(((long long)4 * E + TPB - 1) / TPB);
        int g2E = (int)(((long long)2 * E + TPB - 1) / TPB);

        k_detect<<<1, 256, 0, stream>>>(ei, flag);
        k_deg_init<<<gN, TPB, 0, stream>>>(degi, N);
        k_deg_count<<<gE, TPB, 0, stream>>>(ei, E, flag, degi);
        k_deg_finish<<<gN, TPB, 0, stream>>>(dis, N);
        k_gemm1h<<<gG1, 256, 0, stream>>>(x, W1, b1, h1, N,
                                          ei, E, flag, nullptr, nullptr, 0);
        k_scale<<<(int)(((long long)N * 4 + TPB - 1) / TPB), TPB, 0, stream>>>(
            dis, h1, a1, N, 1);   // a1 = dis^2 * h1
        k_agg1<<<g4E, TPB, 0, stream>>>(ei, E, flag, dis, h1, a1);
        k_gemm2<<<gN, TPB, 0, stream>>>(a1, W2, b2, dis, h2, a2, N);
        k_agg2<<<g2E, TPB, 0, stream>>>(ei, E, flag, dis, h2, a2);
        k_lsm<<<gN, TPB, 0, stream>>>(a2, out, N);
    }
}

// Round 9
// 633.079 us; speedup vs baseline: 1.5563x; 1.5563x over previous
//
#include <hip/hip_runtime.h>
#include <math.h>

constexpr int IN_DIM = 1433;
constexpr int HID    = 16;
constexpr int OUTD   = 7;

// ---------- edge index access (int32 vs int64 auto-detect) ----------
__device__ __forceinline__ int edge_get(const int* __restrict__ ei, long long idx, int is64) {
    return is64 ? ei[2 * idx] : ei[idx];
}

__global__ void k_detect(const int* __restrict__ ei, int* __restrict__ flag) {
    __shared__ int nzsh;
    if (threadIdx.x == 0) nzsh = 0;
    __syncthreads();
    int nz = 0;
    for (int i = threadIdx.x; i < 2048; i += blockDim.x)
        nz |= (ei[2 * i + 1] != 0) ? 1 : 0;
    if (nz) nzsh = 1;
    __syncthreads();
    if (threadIdx.x == 0) *flag = (nzsh == 0) ? 1 : 0;   // 1 => int64
}

// ---------- init ----------
__global__ void k_init_new(int* __restrict__ deg, int* __restrict__ cnt, int n) {
    int i = blockIdx.x * blockDim.x + threadIdx.x;
    if (i < n) { deg[i] = 1; cnt[i] = 0; }
}

__global__ void k_deg_finish(float* __restrict__ dis, int n) {
    int i = blockIdx.x * blockDim.x + threadIdx.x;
    if (i < n) {
        int v = ((const int*)dis)[i];
        dis[i] = rsqrtf((float)v);
    }
}

// ---------- pass 1: degree + CSR slot capture (replaces hist AND fill atomics) ----------
// packed[e] = (dst << 14) | slot ;  slot = arrival index within dst's bucket.
// Max in-degree ~ 32 + 6 sigma << 16384; dst < 2^17 -> fits 31 bits.
__global__ void k_hist2(const int* __restrict__ ei, int E, const int* __restrict__ flag,
                        int* __restrict__ deg, int* __restrict__ cnt,
                        int* __restrict__ packed) {
    int e = blockIdx.x * blockDim.x + threadIdx.x;
    if (e >= E) return;
    int is64 = *flag;
    int s = edge_get(ei, e, is64);
    int d = edge_get(ei, (long long)E + e, is64);
    atomicAdd(&deg[s], 1);                       // fire-and-forget
    int slot = atomicAdd(&cnt[d], 1);            // returning
    packed[e] = (d << 14) | (slot & 16383);
}

// ---------- place: csr[rp[d]+slot] = src  (NO atomics) ----------
__global__ void k_place(const int* __restrict__ ei, int E, const int* __restrict__ flag,
                        const int* __restrict__ packed, const int* __restrict__ rp,
                        int* __restrict__ csr) {
    int e = blockIdx.x * blockDim.x + threadIdx.x;
    if (e >= E) return;
    int is64 = *flag;
    int s  = edge_get(ei, e, is64);
    int p  = packed[e];
    int d  = p >> 14;
    int sl = p & 16383;
    csr[rp[d] + sl] = s;
}

// ---------- 3-kernel exclusive scan of cnt[0..n) -> row_ptr ----------
__global__ __launch_bounds__(256) void k_scan1(const int* __restrict__ cnt,
                                               int* __restrict__ bsum, int n) {
    __shared__ int sh[256];
    int t = threadIdx.x;
    int base = blockIdx.x * 1024 + t * 4;
    int s = 0;
    #pragma unroll
    for (int j = 0; j < 4; ++j) {
        int i = base + j;
        if (i < n) s += cnt[i];
    }
    sh[t] = s; __syncthreads();
    for (int o = 128; o > 0; o >>= 1) {
        if (t < o) sh[t] += sh[t + o];
        __syncthreads();
    }
    if (t == 0) bsum[blockIdx.x] = sh[0];
}

__global__ __launch_bounds__(256) void k_scan2(const int* __restrict__ bsum,
                                               int* __restrict__ boff,
                                               int* __restrict__ rp,
                                               int nb, int n, int E) {
    __shared__ int sh[256];
    int t = threadIdx.x;
    int v = (t < nb) ? bsum[t] : 0;
    sh[t] = v; __syncthreads();
    for (int o = 1; o < 256; o <<= 1) {
        int tmp = (t >= o) ? sh[t - o] : 0;
        __syncthreads();
        sh[t] += tmp;
        __syncthreads();
    }
    boff[t] = sh[t] - v;     // exclusive
    if (t == 0) rp[n] = E;   // total
}

__global__ __launch_bounds__(256) void k_scan3(const int* __restrict__ cnt,
                                               const int* __restrict__ boff,
                                               int* __restrict__ rp, int n) {
    __shared__ int sh[256];
    int t = threadIdx.x;
    int base = blockIdx.x * 1024 + t * 4;
    int c[4];
    int s = 0;
    #pragma unroll
    for (int j = 0; j < 4; ++j) {
        int i = base + j;
        c[j] = (i < n) ? cnt[i] : 0;
        s += c[j];
    }
    sh[t] = s; __syncthreads();
    for (int o = 1; o < 256; o <<= 1) {
        int tmp = (t >= o) ? sh[t - o] : 0;
        __syncthreads();
        sh[t] += tmp;
        __syncthreads();
    }
    int run = boff[blockIdx.x] + sh[t] - s;
    #pragma unroll
    for (int j = 0; j < 4; ++j) {
        int i = base + j;
        if (i < n) rp[i] = run;
        run += c[j];
    }
}

// ---------- GEMM1: h1 = x @ W1 + b1 (raw). Pure gemm, unfused. ----------
// BM=128 rows x 16 cols, BK=32, 128 threads (2 waves).
// Thread (c4 = t&3, rq = t>>2 in 0..31): rows {rq+32j, j<4} x cols c4*4..+3.
// Inner loop reads x from LDS as b128 (4 k at once) -> ~770 LDS-cyc per tile
// per wave vs 1126 for scalar reads. Reg-staged next-tile prefetch.
// No min-waves launch bound (R5 spill lesson). LDS 20.5 KB -> ~6 blocks/CU.
__global__ __launch_bounds__(128) void k_gemm1(
        const float* __restrict__ x, const float* __restrict__ W1,
        const float* __restrict__ b1, float* __restrict__ h1, int n) {
    constexpr int BK = 32, XST = 36;   // 36 floats = 144 B row stride (16B-aligned)
    __shared__ __align__(16) float xs[128 * XST];   // 18.4 KB
    __shared__ __align__(16) float wsm[BK * HID];   // 2 KB
    const int t    = threadIdx.x;
    const int c4   = t & 3;
    const int rq   = t >> 2;           // 0..31
    const int row0 = blockIdx.x * 128;

    float xreg[32];
    float wreg[4];
    float4 acc[4];
    #pragma unroll
    for (int j = 0; j < 4; ++j) acc[j] = make_float4(0.f, 0.f, 0.f, 0.f);

    auto issue = [&](int kt) {
        #pragma unroll
        for (int i = 0; i < 32; ++i) {
            int idx  = t + 128 * i;        // 0..4095
            int srow = idx >> 5;           // 0..127
            int scol = idx & 31;
            int gr   = row0 + srow;
            int col  = kt + scol;
            float v = 0.f;
            if (gr < n && col < IN_DIM) v = x[(long long)gr * IN_DIM + col];
            xreg[i] = v;
        }
        #pragma unroll
        for (int u = 0; u < 4; ++u) {
            int idx = t + 128 * u;         // 0..511
            int kk  = idx >> 4;
            wreg[u] = (kt + kk < IN_DIM) ? W1[(kt + kk) * HID + (idx & 15)] : 0.f;
        }
    };
    auto commit = [&]() {
        #pragma unroll
        for (int i = 0; i < 32; ++i) {
            int idx  = t + 128 * i;
            int srow = idx >> 5;
            int scol = idx & 31;
            xs[srow * XST + scol] = xreg[i];
        }
        #pragma unroll
        for (int u = 0; u < 4; ++u) wsm[t + 128 * u] = wreg[u];
    };

    const int nkt = (IN_DIM + BK - 1) / BK;   // 45
    issue(0);
    for (int it = 0; it < nkt; ++it) {
        commit();
        __syncthreads();
        if (it + 1 < nkt) issue((it + 1) * BK);   // overlaps with compute
        #pragma unroll
        for (int k4 = 0; k4 < BK / 4; ++k4) {
            int k = k4 * 4;
            float4 w0 = *(const float4*)&wsm[(k + 0) * HID + c4 * 4];
            float4 w1 = *(const float4*)&wsm[(k + 1) * HID + c4 * 4];
            float4 w2 = *(const float4*)&wsm[(k + 2) * HID + c4 * 4];
            float4 w3 = *(const float4*)&wsm[(k + 3) * HID + c4 * 4];
            #pragma unroll
            for (int j = 0; j < 4; ++j) {
                float4 xv = *(const float4*)&xs[(rq + 32 * j) * XST + k];
                acc[j].x += xv.x * w0.x + xv.y * w1.x + xv.z * w2.x + xv.w * w3.x;
                acc[j].y += xv.x * w0.y + xv.y * w1.y + xv.z * w2.y + xv.w * w3.y;
                acc[j].z += xv.x * w0.z + xv.y * w1.z + xv.z * w2.z + xv.w * w3.z;
                acc[j].w += xv.x * w0.w + xv.y * w1.w + xv.z * w2.w + xv.w * w3.w;
            }
        }
        __syncthreads();
    }

    float4 bv = *(const float4*)&b1[c4 * 4];
    #pragma unroll
    for (int j = 0; j < 4; ++j) {
        int gr = row0 + rq + 32 * j;
        if (gr < n) {
            float4 hv;
            hv.x = acc[j].x + bv.x;
            hv.y = acc[j].y + bv.y;
            hv.z = acc[j].z + bv.z;
            hv.w = acc[j].w + bv.w;
            *(float4*)&h1[(long long)gr * HID + c4 * 4] = hv;
        }
    }
}

// ---------- scale: out = dis[row]^(1|2) * in  (elementwise, float4) ----------
__global__ void k_scale(const float* __restrict__ dis, const float* __restrict__ in,
                        float* __restrict__ out, int n, int squared) {
    int i = blockIdx.x * blockDim.x + threadIdx.x;   // one float4 per thread
    if (i >= n * 4) return;
    int row = i >> 2;
    float d = dis[row];
    if (squared) d *= d;
    float4 v = *(const float4*)&in[(long long)i * 4];
    v.x *= d; v.y *= d; v.z *= d; v.w *= d;
    *(float4*)&out[(long long)i * 4] = v;
}

// ---------- fused gather1 + gemm2 (pre-scaled inputs), 4-deep pipelined ----------
__global__ __launch_bounds__(256) void k_gather1f(
        const int* __restrict__ rp, const int* __restrict__ csr,
        const float* __restrict__ dis, const float* __restrict__ hs1,
        const float* __restrict__ W2, const float* __restrict__ b2,
        float* __restrict__ hs2, int n) {
    __shared__ float w2s[HID * OUTD];
    __shared__ float b2s[OUTD];
    int t = threadIdx.x;
    if (t < HID * OUTD) w2s[t] = W2[t];
    if (t < OUTD) b2s[t] = b2[t];
    __syncthreads();

    int tid  = blockIdx.x * blockDim.x + t;
    int node = tid >> 2;
    int q    = tid & 3;
    if (node >= n) return;

    float4 acc = *(const float4*)&hs1[(long long)node * HID + q * 4];  // self term

    int i = rp[node], end = rp[node + 1];
    for (; i + 4 <= end; i += 4) {
        int s0 = csr[i], s1 = csr[i + 1], s2 = csr[i + 2], s3 = csr[i + 3];
        float4 h0 = *(const float4*)&hs1[(long long)s0 * HID + q * 4];
        float4 h1 = *(const float4*)&hs1[(long long)s1 * HID + q * 4];
        float4 h2 = *(const float4*)&hs1[(long long)s2 * HID + q * 4];
        float4 h3 = *(const float4*)&hs1[(long long)s3 * HID + q * 4];
        acc.x += (h0.x + h1.x) + (h2.x + h3.x);
        acc.y += (h0.y + h1.y) + (h2.y + h3.y);
        acc.z += (h0.z + h1.z) + (h2.z + h3.z);
        acc.w += (h0.w + h1.w) + (h2.w + h3.w);
    }
    for (; i < end; ++i) {
        int s = csr[i];
        float4 h = *(const float4*)&hs1[(long long)s * HID + q * 4];
        acc.x += h.x; acc.y += h.y; acc.z += h.z; acc.w += h.w;
    }

    float dn = dis[node];
    float r0 = fmaxf(dn * acc.x, 0.f), r1 = fmaxf(dn * acc.y, 0.f);
    float r2 = fmaxf(dn * acc.z, 0.f), r3 = fmaxf(dn * acc.w, 0.f);
    float p[OUTD];
    #pragma unroll
    for (int j = 0; j < OUTD; ++j) {
        p[j] = r0 * w2s[(q * 4 + 0) * OUTD + j]
             + r1 * w2s[(q * 4 + 1) * OUTD + j]
             + r2 * w2s[(q * 4 + 2) * OUTD + j]
             + r3 * w2s[(q * 4 + 3) * OUTD + j];
    }
    #pragma unroll
    for (int j = 0; j < OUTD; ++j) {
        p[j] += __shfl_xor(p[j], 1, 4);
        p[j] += __shfl_xor(p[j], 2, 4);
    }
    hs2[(long long)node * OUTD + q] = dn * (p[q] + b2s[q]);
    if (q < 3) hs2[(long long)node * OUTD + q + 4] = dn * (p[q + 4] + b2s[q + 4]);
}

// ---------- gather2 + log_softmax fused (pre-scaled), 8-deep pipelined ----------
__global__ __launch_bounds__(256) void k_gather2(
        const int* __restrict__ rp, const int* __restrict__ csr,
        const float* __restrict__ dis, const float* __restrict__ hs2,
        float* __restrict__ out, int n) {
    int t = threadIdx.x;
    int node = blockIdx.x * 32 + (t >> 3);
    int q = t & 7;
    if (node >= n) return;
    float acc = -1e30f;
    if (q < OUTD) {
        acc = hs2[(long long)node * OUTD + q];   // self term
        int i = rp[node], end = rp[node + 1];
        for (; i + 8 <= end; i += 8) {
            int s0 = csr[i],     s1 = csr[i + 1], s2 = csr[i + 2], s3 = csr[i + 3];
            int s4 = csr[i + 4], s5 = csr[i + 5], s6 = csr[i + 6], s7 = csr[i + 7];
            float v0 = hs2[(long long)s0 * OUTD + q];
            float v1 = hs2[(long long)s1 * OUTD + q];
            float v2 = hs2[(long long)s2 * OUTD + q];
            float v3 = hs2[(long long)s3 * OUTD + q];
            float v4 = hs2[(long long)s4 * OUTD + q];
            float v5 = hs2[(long long)s5 * OUTD + q];
            float v6 = hs2[(long long)s6 * OUTD + q];
            float v7 = hs2[(long long)s7 * OUTD + q];
            acc += ((v0 + v1) + (v2 + v3)) + ((v4 + v5) + (v6 + v7));
        }
        for (; i < end; ++i) {
            int s = csr[i];
            acc += hs2[(long long)s * OUTD + q];
        }
        acc *= dis[node];
    }
    float m = acc;
    #pragma unroll
    for (int o = 1; o < 8; o <<= 1) m = fmaxf(m, __shfl_xor(m, o, 8));
    float ex = (q < OUTD) ? expf(acc - m) : 0.f;
    float ss = ex;
    #pragma unroll
    for (int o = 1; o < 8; o <<= 1) ss += __shfl_xor(ss, o, 8);
    if (q < OUTD) out[(long long)node * OUTD + q] = acc - m - logf(ss);
}

// ---------- fallback-only kernels (atomic path) ----------
__global__ void k_deg_init(int* __restrict__ deg, int n) {
    int i = blockIdx.x * blockDim.x + threadIdx.x;
    if (i < n) deg[i] = 1;
}

__global__ void k_deg_count(const int* __restrict__ ei, int E,
                            const int* __restrict__ flag, int* __restrict__ deg) {
    int e = blockIdx.x * blockDim.x + threadIdx.x;
    if (e >= E) return;
    int is64 = *flag;
    int s = edge_get(ei, e, is64);
    atomicAdd(&deg[s], 1);
}

__global__ void k_agg1(const int* __restrict__ ei, int E, const int* __restrict__ flag,
                       const float* __restrict__ dis, const float* __restrict__ h1,
                       float* __restrict__ a1) {
    long long tid = (long long)blockIdx.x * blockDim.x + threadIdx.x;
    int e = (int)(tid >> 2);
    int q = (int)(tid & 3);
    if (e >= E) return;
    int is64 = *flag;
    int s = edge_get(ei, e, is64);
    int d = edge_get(ei, (long long)E + e, is64);
    float nrm = dis[s] * dis[d];
    float4 v = *(const float4*)&h1[(long long)s * HID + q * 4];
    float* o = &a1[(long long)d * HID + q * 4];
    atomicAdd(o + 0, nrm * v.x);
    atomicAdd(o + 1, nrm * v.y);
    atomicAdd(o + 2, nrm * v.z);
    atomicAdd(o + 3, nrm * v.w);
}

__global__ __launch_bounds__(256) void k_gemm2(
        const float* __restrict__ a1, const float* __restrict__ W2,
        const float* __restrict__ b2, const float* __restrict__ dis,
        float* __restrict__ h2, float* __restrict__ a2, int n) {
    __shared__ float w2s[HID * OUTD];
    __shared__ float b2s[OUTD];
    int t = threadIdx.x;
    if (t < HID * OUTD) w2s[t] = W2[t];
    if (t < OUTD) b2s[t] = b2[t];
    __syncthreads();
    int r = blockIdx.x * blockDim.x + t;
    if (r >= n) return;
    float a[16];
    #pragma unroll
    for (int i = 0; i < 4; ++i) {
        float4 v = *(const float4*)&a1[(long long)r * HID + i * 4];
        a[4 * i + 0] = fmaxf(v.x, 0.f);
        a[4 * i + 1] = fmaxf(v.y, 0.f);
        a[4 * i + 2] = fmaxf(v.z, 0.f);
        a[4 * i + 3] = fmaxf(v.w, 0.f);
    }
    float dd = 0.f;
    if (a2) { float d = dis[r]; dd = d * d; }
    #pragma unroll
    for (int j = 0; j < OUTD; ++j) {
        float acc = b2s[j];
        #pragma unroll
        for (int k = 0; k < HID; ++k) acc += a[k] * w2s[k * OUTD + j];
        h2[(long long)r * OUTD + j] = acc;
        if (a2) a2[(long long)r * OUTD + j] = dd * acc;
    }
}

__global__ void k_agg2(const int* __restrict__ ei, int E, const int* __restrict__ flag,
                       const float* __restrict__ dis, const float* __restrict__ h2,
                       float* __restrict__ a2) {
    long long tid = (long long)blockIdx.x * blockDim.x + threadIdx.x;
    int e = (int)(tid >> 1);
    int q = (int)(tid & 1);
    if (e >= E) return;
    int is64 = *flag;
    int s = edge_get(ei, e, is64);
    int d = edge_get(ei, (long long)E + e, is64);
    float nrm = dis[s] * dis[d];
    int cnt = q ? 3 : 4;
    long long bs = (long long)s * OUTD + q * 4;
    long long bd = (long long)d * OUTD + q * 4;
    #pragma unroll
    for (int j = 0; j < 4; ++j)
        if (j < cnt) atomicAdd(&a2[bd + j], nrm * h2[bs + j]);
}

__global__ void k_lsm(const float* __restrict__ a2, float* __restrict__ out, int n) {
    int r = blockIdx.x * blockDim.x + threadIdx.x;
    if (r >= n) return;
    float v[OUTD];
    #pragma unroll
    for (int j = 0; j < OUTD; ++j) v[j] = a2[(long long)r * OUTD + j];
    float m = v[0];
    #pragma unroll
    for (int j = 1; j < OUTD; ++j) m = fmaxf(m, v[j]);
    float ssum = 0.f;
    #pragma unroll
    for (int j = 0; j < OUTD; ++j) ssum += expf(v[j] - m);
    float l = logf(ssum);
    #pragma unroll
    for (int j = 0; j < OUTD; ++j) out[(long long)r * OUTD + j] = v[j] - m - l;
}

extern "C" void kernel_launch(void* const* d_in, const int* in_sizes, int n_in,
                              void* d_out, int out_size, void* d_ws, size_t ws_size,
                              hipStream_t stream) {
    const float* x  = (const float*)d_in[0];
    const int*   ei = (const int*)d_in[1];
    const float* W1 = (const float*)d_in[2];
    const float* b1 = (const float*)d_in[3];
    const float* W2 = (const float*)d_in[4];
    const float* b2 = (const float*)d_in[5];
    float* out = (float*)d_out;

    const int N = in_sizes[0] / IN_DIM;   // 100000
    const int E = in_sizes[1] / 2;        // 3200000

    const int TPB = 256;
    const int gN  = (N + TPB - 1) / TPB;
    const int gE  = (E + TPB - 1) / TPB;
    const int gG1 = (N + 127) / 128;      // gemm blocks (128 threads, 128 rows)
    const int NB  = (N + 1023) / 1024;

    float* ws = (float*)d_ws;
    size_t o = 0;
    auto take = [&](size_t cnt) { size_t r = o; o += (cnt + 127) & ~(size_t)127; return r; };

    size_t off_dis  = take((size_t)N);
    size_t off_flag = take(64);
    size_t off_cnt  = take((size_t)N);
    size_t off_rp   = take((size_t)N + 1);
    size_t off_bs   = take(256);
    size_t off_bo   = take(256);
    size_t off_pk   = take((size_t)E);
    size_t off_csr  = take((size_t)E);
    size_t off_h1   = take((size_t)N * HID);
    size_t off_h2   = take((size_t)N * OUTD);
    size_t need_new = o * sizeof(float);

    if (ws_size >= need_new) {
        float* dis  = ws + off_dis;
        int*   degi = (int*)dis;
        int*   flag = (int*)(ws + off_flag);
        int*   cnt  = (int*)(ws + off_cnt);
        int*   rp   = (int*)(ws + off_rp);
        int*   bs   = (int*)(ws + off_bs);
        int*   bo   = (int*)(ws + off_bo);
        int*   pk   = (int*)(ws + off_pk);
        int*   csr  = (int*)(ws + off_csr);
        float* h1   = ws + off_h1;   // raw h1, then scaled in-place -> hs1
        float* hs2  = ws + off_h2;

        k_detect<<<1, 256, 0, stream>>>(ei, flag);
        k_init_new<<<gN, TPB, 0, stream>>>(degi, cnt, N);
        k_hist2<<<gE, TPB, 0, stream>>>(ei, E, flag, degi, cnt, pk);
        k_deg_finish<<<gN, TPB, 0, stream>>>(dis, N);
        k_scan1<<<NB, 256, 0, stream>>>(cnt, bs, N);
        k_scan2<<<1, 256, 0, stream>>>(bs, bo, rp, NB, N, E);
        k_scan3<<<NB, 256, 0, stream>>>(cnt, bo, rp, N);
        k_place<<<gE, TPB, 0, stream>>>(ei, E, flag, pk, rp, csr);
        k_gemm1<<<gG1, 128, 0, stream>>>(x, W1, b1, h1, N);
        k_scale<<<(int)(((long long)N * 4 + TPB - 1) / TPB), TPB, 0, stream>>>(
            dis, h1, h1, N, 0);   // hs1 = dis * h1 (in-place)
        k_gather1f<<<(int)(((long long)N * 4 + TPB - 1) / TPB), TPB, 0, stream>>>(
            rp, csr, dis, h1, W2, b2, hs2, N);
        k_gather2<<<(N + 31) / 32, 256, 0, stream>>>(rp, csr, dis, hs2, out, N);
    } else {
        o = 0;
        size_t f_dis  = take((size_t)N);
        size_t f_flag = take(64);
        size_t f_h1   = take((size_t)N * HID);
        size_t f_a1   = take((size_t)N * HID);
        size_t f_h2   = take((size_t)N * OUTD);
        size_t f_a2   = take((size_t)N * OUTD);

        float* dis  = ws + f_dis;
        int*   degi = (int*)dis;
        int*   flag = (int*)(ws + f_flag);
        float* h1   = ws + f_h1;
        float* a1   = ws + f_a1;
        float* h2   = ws + f_h2;
        float* a2   = ws + f_a2;

        int g4E = (int)(((long long)4 * E + TPB - 1) / TPB);
        int g2E = (int)(((long long)2 * E + TPB - 1) / TPB);

        k_detect<<<1, 256, 0, stream>>>(ei, flag);
        k_deg_init<<<gN, TPB, 0, stream>>>(degi, N);
        k_deg_count<<<gE, TPB, 0, stream>>>(ei, E, flag, degi);
        k_deg_finish<<<gN, TPB, 0, stream>>>(dis, N);
        k_gemm1<<<gG1, 128, 0, stream>>>(x, W1, b1, h1, N);
        k_scale<<<(int)(((long long)N * 4 + TPB - 1) / TPB), TPB, 0, stream>>>(
            dis, h1, a1, N, 1);   // a1 = dis^2 * h1
        k_agg1<<<g4E, TPB, 0, stream>>>(ei, E, flag, dis, h1, a1);
        k_gemm2<<<gN, TPB, 0, stream>>>(a1, W2, b2, dis, h2, a2, N);
        k_agg2<<<g2E, TPB, 0, stream>>>(ei, E, flag, dis, h2, a2);
        k_lsm<<<gN, TPB, 0, stream>>>(a2, out, N);
    }
}